// Round 7
// baseline (256.635 us; speedup 1.0000x reference)
//
#include <hip/hip_runtime.h>

// Sparse (local + vertical-stride) causal attention, MI355X gfx950.
// B=1, S=2048, H=32, D=128, BLOCK=64, LOCAL=16, VERT=8, SLIDE=1, OFFSET=0.
// R7: 128-q blocks, 4 waves x 32 q/wave (two q-halves share every Ks/Vp
// fragment read -> LDS traffic per work halved). Transposed MFMA pipeline
// (S^T = K Q^T, O^T = V^T P^T), permuted K rows (krow) so S^T C-layout ==
// 16x16x32 B-operand layout; P in registers; lane-local softmax; K staged
// with conflict-free full-row b128 writes; lgkm-only in-loop barriers.

#define NH 32
#define HD 128

typedef __attribute__((ext_vector_type(8))) short short8;
typedef __attribute__((ext_vector_type(4))) float f32x4;

static __device__ __forceinline__ unsigned f2u(float f) {
    union { float f; unsigned u; } x; x.f = f; return x.u;
}
static __device__ __forceinline__ unsigned bfpk(float a, float b) {
    return ((f2u(a) + 0x8000u) >> 16) | ((f2u(b) + 0x8000u) & 0xFFFF0000u);
}
static __device__ __forceinline__ unsigned short f2bf(float f) {
    return (unsigned short)((f2u(f) + 0x8000u) >> 16);
}

// In-loop barrier waiting only on LDS ops — global prefetch stays in flight.
static __device__ __forceinline__ void wg_barrier() {
    asm volatile("" ::: "memory");
    __builtin_amdgcn_s_waitcnt(0xC07F);   // vmcnt(63) expcnt(7) lgkmcnt(0)
    __builtin_amdgcn_s_barrier();
    asm volatile("" ::: "memory");
}

// key 32c+8q+4e+r -> LDS row 32c+16e+4q+r (bijection): S^T C-layout rows
// become exactly the 16x16x32 B-operand k-order.
static __device__ __forceinline__ int krow(int kk) {
    return (kk & 3) | (((kk >> 2) & 1) << 4) | (((kk >> 3) & 3) << 2) | (kk & 32);
}

__global__ __launch_bounds__(256)
void sparse_attn_kernel(const float* __restrict__ Q,
                        const float* __restrict__ K,
                        const float* __restrict__ V,
                        float* __restrict__ O)
{
    // LPT (heavy qmb first) + XCD head clustering; 512 blocks
    const int id   = blockIdx.x;
    const int h    = (id & 7) * 4 + ((id >> 3) & 3);
    const int qmb  = 15 - (id >> 5);          // 128-query macroblock
    const int qbA  = qmb * 2;                 // lower 64-q block
    const int qbB  = qbA + 1;                 // upper 64-q block

    const int tid  = threadIdx.x;
    const int wave = tid >> 6;
    const int lane = tid & 63;
    const int m16  = lane & 15;
    const int quad = lane >> 4;

    // Aliased LDS: staging (Ks 17408 + Vp 18432 = 35840 B) vs epilogue 33792 B
    __shared__ __align__(16) char smem[64 * 136 * 2 + 128 * 36 * 4];
    unsigned short (*Ks)[136] = reinterpret_cast<unsigned short(*)[136]>(smem);   // [perm key][d]
    unsigned (*Vp)[36] = reinterpret_cast<unsigned(*)[36]>(smem + 64 * 136 * 2);  // [d][key-pair]

    // ---- Q fragments for both halves, scale*log2e folded ----
    const float QSC = 0.08838834764831845f * 1.44269504088896f;
    short8 qf[2][4];
    #pragma unroll
    for (int hx = 0; hx < 2; ++hx) {
        const int qrow = qmb * 128 + hx * 64 + wave * 16 + m16;
        const float* qp = Q + ((size_t)qrow * NH + h) * HD + quad * 8;
        #pragma unroll
        for (int ks = 0; ks < 4; ++ks) {
            const float4 a = *reinterpret_cast<const float4*>(qp + ks * 32);
            const float4 b = *reinterpret_cast<const float4*>(qp + ks * 32 + 4);
            short8 f;
            f[0]=(short)f2bf(a.x*QSC); f[1]=(short)f2bf(a.y*QSC);
            f[2]=(short)f2bf(a.z*QSC); f[3]=(short)f2bf(a.w*QSC);
            f[4]=(short)f2bf(b.x*QSC); f[5]=(short)f2bf(b.y*QSC);
            f[6]=(short)f2bf(b.z*QSC); f[7]=(short)f2bf(b.w*QSC);
            qf[hx][ks] = f;
        }
    }

    // O^T accumulators per half: lane owns q=m16; rows d = dt*16+quad*4+reg
    f32x4 acc[2][8];
    #pragma unroll
    for (int hx = 0; hx < 2; ++hx)
        #pragma unroll
        for (int dt = 0; dt < 8; ++dt) {
            acc[hx][dt][0]=0.f; acc[hx][dt][1]=0.f;
            acc[hx][dt][2]=0.f; acc[hx][dt][3]=0.f;
        }
    float mrow[2] = { -3.0e38f, -3.0e38f };
    float lrow[2] = { 0.f, 0.f };

    // staging coordinates
    const int kkey0 = tid >> 4;                 // + it*16 (16 lanes per key row)
    const int kd8   = (tid & 15) << 3;          // full-row b128: d = kd8..kd8+7
    const int vkey0 = wave * 8 + (lane & 7);
    const int vd40  = (lane >> 3) << 2;
    const int vc    = wave * 4 + ((lane & 7) >> 1);

    const int lb = qbB - 16;   // union local window start
    int kb = 0;
    while (!((kb >= lb) || (((kb + h + 1) & 7) == 0))) ++kb;

    float4 kreg[8], vreg[8];
    {
        const float* kp = K + (size_t)kb * 262144 + (size_t)kkey0 * 4096 + h * 128 + kd8;
        #pragma unroll
        for (int it = 0; it < 4; ++it) {
            kreg[2*it]   = *reinterpret_cast<const float4*>(kp + it * 65536);
            kreg[2*it+1] = *reinterpret_cast<const float4*>(kp + it * 65536 + 4);
        }
        const float* vp = V + (size_t)kb * 262144 + (size_t)vkey0 * 4096 + h * 128 + vd40;
        #pragma unroll
        for (int it = 0; it < 8; ++it)
            vreg[it] = *reinterpret_cast<const float4*>(vp + (it & 1) * 131072 + (it >> 1) * 32);
    }

    while (kb <= qbB) {
        int nkb = kb + 1;
        while (nkb <= qbB && !((nkb >= lb) || (((nkb + h + 1) & 7) == 0))) ++nkb;

        const bool vert = ((kb + h + 1) & 7) == 0;
        const bool actA = kb < qbB;                  // kb <= qbA, given union
        const bool actB = (kb >= qbB - 15) || vert;

        wg_barrier();   // all waves' LDS reads of prev iteration retired

        // ---- stage K: full-row b128 (conflict-free via krow), re-prefetch ----
        #pragma unroll
        for (int it = 0; it < 4; ++it) {
            const float4 a = kreg[2*it], b = kreg[2*it+1];
            uint4 pk;
            pk.x = bfpk(a.x, a.y); pk.y = bfpk(a.z, a.w);
            pk.z = bfpk(b.x, b.y); pk.w = bfpk(b.z, b.w);
            *reinterpret_cast<uint4*>(&Ks[krow(it * 16 + kkey0)][kd8]) = pk;
        }
        if (nkb <= qbB) {
            const float* kp = K + (size_t)nkb * 262144 + (size_t)kkey0 * 4096 + h * 128 + kd8;
            #pragma unroll
            for (int it = 0; it < 4; ++it) {
                kreg[2*it]   = *reinterpret_cast<const float4*>(kp + it * 65536);
                kreg[2*it+1] = *reinterpret_cast<const float4*>(kp + it * 65536 + 4);
            }
        }

        // ---- stage V transposed (pair-packed b32), re-prefetch ----
        #pragma unroll
        for (int it = 0; it < 8; ++it) {
            const int d4 = (it >> 1) * 32 + vd40;
            const float4 vv = vreg[it];
            const unsigned p0 = bfpk(vv.x, vv.y);
            const unsigned p1 = bfpk(vv.z, vv.w);
            const unsigned q0 = __shfl_xor(p0, 1);
            const unsigned q1 = __shfl_xor(p1, 1);
            const int c = (it & 1) * 16 + vc;
            if ((lane & 1) == 0) {
                Vp[d4 + 0][c] = (p0 & 0xFFFFu) | (q0 << 16);
                Vp[d4 + 1][c] = (p0 >> 16)     | (q0 & 0xFFFF0000u);
            } else {
                Vp[d4 + 2][c] = (q1 & 0xFFFFu) | (p1 << 16);
                Vp[d4 + 3][c] = (q1 >> 16)     | (p1 & 0xFFFF0000u);
            }
        }
        if (nkb <= qbB) {
            const float* vp = V + (size_t)nkb * 262144 + (size_t)vkey0 * 4096 + h * 128 + vd40;
            #pragma unroll
            for (int it = 0; it < 8; ++it)
                vreg[it] = *reinterpret_cast<const float4*>(vp + (it & 1) * 131072 + (it >> 1) * 32);
        }

        wg_barrier();   // staging visible

        // ---- S^T = K Q^T for both halves; each Ks frag read feeds 2 MFMAs ----
        f32x4 sc[2][4];
        #pragma unroll
        for (int hx = 0; hx < 2; ++hx)
            #pragma unroll
            for (int nt = 0; nt < 4; ++nt) {
                sc[hx][nt][0]=0.f; sc[hx][nt][1]=0.f;
                sc[hx][nt][2]=0.f; sc[hx][nt][3]=0.f;
            }
        #pragma unroll
        for (int nt = 0; nt < 4; ++nt) {
            #pragma unroll
            for (int ks = 0; ks < 4; ++ks) {
                const short8 a = *reinterpret_cast<const short8*>(&Ks[nt * 16 + m16][ks * 32 + quad * 8]);
                if (actA) sc[0][nt] = __builtin_amdgcn_mfma_f32_16x16x32_bf16(a, qf[0][ks], sc[0][nt], 0, 0, 0);
                if (actB) sc[1][nt] = __builtin_amdgcn_mfma_f32_16x16x32_bf16(a, qf[1][ks], sc[1][nt], 0, 0, 0);
            }
        }

        // ---- diagonal causal masks (actual key index; wave-uniform guards) ----
        #pragma unroll
        for (int hx = 0; hx < 2; ++hx) {
            if (kb == qbA + hx) {
                const int qloc = wave * 16 + m16;
                #pragma unroll
                for (int nt = 0; nt < 4; ++nt) {
                    const int kb0 = (nt >> 1) * 32 + quad * 8 + (nt & 1) * 4;
                    #pragma unroll
                    for (int r = 0; r < 4; ++r)
                        if (kb0 + r > qloc) sc[hx][nt][r] = -1.0e30f;
                }
            }
        }

        // ---- lane-local online softmax + P^T frags + PV, per half ----
        short8 pf[2][2];
        #pragma unroll
        for (int hx = 0; hx < 2; ++hx) {
            const bool act = hx ? actB : actA;
            if (!act) continue;
            float mx = sc[hx][0][0];
            #pragma unroll
            for (int nt = 0; nt < 4; ++nt)
                #pragma unroll
                for (int r = 0; r < 4; ++r) mx = fmaxf(mx, sc[hx][nt][r]);
            mx = fmaxf(mx, __shfl_xor(mx, 16));
            mx = fmaxf(mx, __shfl_xor(mx, 32));
            const float mnew = fmaxf(mrow[hx], mx);
            const float alpha = __builtin_exp2f(mrow[hx] - mnew);
            lrow[hx] *= alpha;
            #pragma unroll
            for (int dt = 0; dt < 8; ++dt) {
                acc[hx][dt][0] *= alpha; acc[hx][dt][1] *= alpha;
                acc[hx][dt][2] *= alpha; acc[hx][dt][3] *= alpha;
            }
            float rs = 0.f;
            #pragma unroll
            for (int nt = 0; nt < 4; ++nt)
                #pragma unroll
                for (int r = 0; r < 4; ++r) {
                    const float p = __builtin_exp2f(sc[hx][nt][r] - mnew);
                    sc[hx][nt][r] = p;
                    rs += p;
                }
            rs += __shfl_xor(rs, 16);
            rs += __shfl_xor(rs, 32);
            lrow[hx] += rs;
            mrow[hx] = mnew;

            #pragma unroll
            for (int c = 0; c < 2; ++c) {
                union { unsigned u[4]; short8 s; } cv;
                cv.u[0] = bfpk(sc[hx][2*c][0],   sc[hx][2*c][1]);
                cv.u[1] = bfpk(sc[hx][2*c][2],   sc[hx][2*c][3]);
                cv.u[2] = bfpk(sc[hx][2*c+1][0], sc[hx][2*c+1][1]);
                cv.u[3] = bfpk(sc[hx][2*c+1][2], sc[hx][2*c+1][3]);
                pf[hx][c] = cv.s;
            }
        }

        // ---- O^T += V^T P^T; each Vp frag read feeds both halves ----
        #pragma unroll
        for (int dt = 0; dt < 8; ++dt) {
            #pragma unroll
            for (int c = 0; c < 2; ++c) {
                const short8 a = *reinterpret_cast<const short8*>(
                    &Vp[dt * 16 + m16][c * 16 + quad * 4]);
                if (actA) acc[0][dt] = __builtin_amdgcn_mfma_f32_16x16x32_bf16(a, pf[0][c], acc[0][dt], 0, 0, 0);
                if (actB) acc[1][dt] = __builtin_amdgcn_mfma_f32_16x16x32_bf16(a, pf[1][c], acc[1][dt], 0, 0, 0);
            }
        }

        kb = nkb;
    }

    // ---- epilogue: per half, O^T -> LDS transpose -> coalesced stores ----
    float* Osf = reinterpret_cast<float*>(smem);   // [64 q][132 d], 33792 B
    #pragma unroll
    for (int hx = 0; hx < 2; ++hx) {
        __syncthreads();   // full drain before aliasing / reusing Osf
        {
            const float inv = 1.0f / lrow[hx];
            const int q = wave * 16 + m16;
            #pragma unroll
            for (int dt = 0; dt < 8; ++dt) {
                f32x4 v = acc[hx][dt];
                v[0] *= inv; v[1] *= inv; v[2] *= inv; v[3] *= inv;
                *reinterpret_cast<f32x4*>(&Osf[q * 132 + dt * 16 + quad * 4]) = v;
            }
        }
        __syncthreads();
        const int qbase = qmb * 128 + hx * 64;
        #pragma unroll
        for (int p = 0; p < 2; ++p) {
            const int row = p * 32 + (tid >> 3);
            const int dbase = (tid & 7) * 4;
            #pragma unroll
            for (int i = 0; i < 4; ++i) {
                const int d = i * 32 + dbase;
                const f32x4 v = *reinterpret_cast<const f32x4*>(&Osf[row * 132 + d]);
                *reinterpret_cast<f32x4*>(O + ((size_t)(qbase + row) * NH + h) * HD + d) = v;
            }
        }
    }
}

extern "C" void kernel_launch(void* const* d_in, const int* in_sizes, int n_in,
                              void* d_out, int out_size, void* d_ws, size_t ws_size,
                              hipStream_t stream) {
    const float* q = (const float*)d_in[0];
    const float* k = (const float*)d_in[1];
    const float* v = (const float*)d_in[2];
    float* out = (float*)d_out;
    sparse_attn_kernel<<<dim3(512), dim3(256), 0, stream>>>(q, k, v, out);
}